// Round 11
// baseline (1873.696 us; speedup 1.0000x reference)
//
#include <hip/hip_runtime.h>

#define NTOK 2560
#define NN ((long)NTOK*NTOK)

// flag indices
#define C_CTR 0
#define G_CTR 1
#define Q_TOT 2
#define QS 3
#define AS 43
#define PS 83
#define MS 123
#define AF 163
#define NCOMP 2080
#define NCARGO 3712

typedef __attribute__((ext_vector_type(8))) short short8;
typedef __attribute__((ext_vector_type(4))) float f32x4;

__device__ __forceinline__ unsigned short f2bf(float f){
  union { float f; unsigned int u; } v; v.f = f;
  unsigned int u = v.u + 0x7fffu + ((v.u >> 16) & 1u);
  return (unsigned short)(u >> 16);
}

__device__ __forceinline__ f32x4 mfma16(short8 a, short8 b, f32x4 c){
  return __builtin_amdgcn_mfma_f32_16x16x32_bf16(a, b, c, 0, 0, 0);
}

__device__ __forceinline__ int ldF(int* F, int i){ return atomicAdd(&F[i], 0); }

// ------------- tiled weight transpose: fp32 [K][N] -> bf16 [N][K], 64x64 tiles -------------
__global__ __launch_bounds__(256) void wt_all_k(
    const float* __restrict__ Wqkv, const float* __restrict__ Wproj,
    const float* __restrict__ W1, const float* __restrict__ W2,
    unsigned short* __restrict__ wqkvt, unsigned short* __restrict__ wprojt,
    unsigned short* __restrict__ w1t, unsigned short* __restrict__ w2t)
{
  __shared__ unsigned short T[64][68];
  int j = blockIdx.x;               // < 384
  int d = j >= 192; j -= d*192;
  const float* src; unsigned short* dst; int K, N, tk, tn;
  if (j < 48){        src = Wqkv  + d*196608; dst = wqkvt  + d*196608; K=256;  N=768;  tk=j/12; tn=j-tk*12; }
  else if (j < 64){   j-=48;  src = Wproj + d*65536;  dst = wprojt + d*65536;  K=256;  N=256;  tk=j>>2; tn=j&3; }
  else if (j < 128){  j-=64;  src = W1    + d*262144; dst = w1t    + d*262144; K=256;  N=1024; tk=j>>4; tn=j&15; }
  else {              j-=128; src = W2    + d*262144; dst = w2t    + d*262144; K=1024; N=256;  tk=j>>2; tn=j&3; }
  int k0 = tk*64, n0 = tn*64;
  int r = threadIdx.x >> 2, c0 = (threadIdx.x & 3) * 16;
  const float* p = src + (long)(k0+r)*N + n0 + c0;
  #pragma unroll
  for (int e4 = 0; e4 < 4; e4++){
    f32x4 v = *(const f32x4*)(p + e4*4);
    #pragma unroll
    for (int e = 0; e < 4; e++) T[r][c0 + e4*4 + e] = f2bf(v[e]);
  }
  __syncthreads();
  unsigned short* q = dst + (long)(n0+r)*K + k0 + c0;
  short8 o0, o1;
  #pragma unroll
  for (int e = 0; e < 8; e++){ o0[e] = (short)T[c0+e][r]; o1[e] = (short)T[c0+8+e][r]; }
  *(short8*)q = o0;
  *(short8*)(q+8) = o1;
}

// ------------- zero cargo: u in [0,2560) -------------
__device__ void zero_unit_body(int u, const int* __restrict__ mask,
                               float* __restrict__ attn_out)
{
  int h = u / 320, rem = u - h*320;
  int tile, cb;
  if (rem < 256){
    tile = rem >> 2;
    int zi = rem & 3, rblk = tile >> 4;
    cb = zi + (zi >= rblk);
  } else {
    int fz = rem - 256;
    tile = 64 + (fz >> 2);
    cb = fz & 3;
    if (mask[cb] == 1) return;
  }
  long base = (long)h*NN + (long)tile*32*NTOK + cb*512;
  f32x4 z = {0.f,0.f,0.f,0.f};
  int tid = threadIdx.x;
  #pragma unroll
  for (int i=0;i<16;i++){
    int idx = tid + i*256;
    int rl = idx >> 7, c4 = (idx & 127) << 2;
    *(f32x4*)&attn_out[base + (long)rl*NTOK + c4] = z;
  }
}

// ------------- allowed-P emission unit: u in [0,1152) -------------
__device__ void p_unit_body(
    int u, const unsigned short* __restrict__ qbf, const unsigned short* __restrict__ kbf,
    const float* __restrict__ rinv_ws, float* __restrict__ attn_out,
    const int* __restrict__ mask, char* smem)
{
  if (u >= 1152) return;
  int h, tile, cb;
  if (u < 512){ h = u >> 6; tile = u & 63; cb = tile >> 4; }
  else if (u < 640){ int v = u - 512; h = v >> 4; tile = 64 + (v & 15); cb = 4; }
  else { int v = u - 640; h = v >> 6; tile = 64 + ((v >> 2) & 15); cb = v & 3; if (mask[cb] != 1) return; }
  float (*P32)[268] = (float (*)[268])smem;
  int tid = threadIdx.x, lane = tid & 63, w = tid >> 6;
  int row0 = tile * 32;
  long base = (long)h*NN + (long)row0*NTOK + cb*512;
  int kk = (lane>>4)*8, l15 = lane & 15, rgrp = (lane>>4)*4;
  short8 aq0 = *(const short8*)&qbf[(h*NTOK + row0 + l15)*32 + kk];
  short8 aq1 = *(const short8*)&qbf[(h*NTOK + row0 + 16 + l15)*32 + kk];
  float rinv[8];
  #pragma unroll
  for (int r=0;r<4;r++){
    rinv[r]   = rinv_ws[h*NTOK + row0 + rgrp + r];
    rinv[4+r] = rinv_ws[h*NTOK + row0 + 16 + rgrp + r];
  }
  #pragma unroll
  for (int hf=0; hf<2; hf++){
    #pragma unroll
    for (int ct=0; ct<4; ct++){
      int cl = w*64 + ct*16 + l15;
      short8 bk = *(const short8*)&kbf[(h*NTOK + cb*512 + hf*256 + cl)*32 + kk];
      f32x4 s0 = {}; s0 = mfma16(aq0, bk, s0);
      f32x4 s1 = {}; s1 = mfma16(aq1, bk, s1);
      #pragma unroll
      for (int r=0;r<4;r++){
        P32[rgrp + r][cl]      = __expf(s0[r]) * rinv[r];
        P32[16 + rgrp + r][cl] = __expf(s1[r]) * rinv[4+r];
      }
    }
    __syncthreads();
    long hbase = base + hf*256;
    #pragma unroll
    for (int j=0;j<8;j++){
      int qi = j*256 + tid;
      int rl = qi >> 6, qc = (qi & 63)*4;
      *(f32x4*)&attn_out[hbase + (long)rl*NTOK + qc] = *(const f32x4*)&P32[rl][qc];
    }
    __syncthreads();
  }
}

// ------------- GEMM unit (runtime epi/ln), 64x64 tile, full-256 K staging -------------
// epi 0: QKV scatter; 1: xout = xin + v + bias; 2: gelu(v+bias) -> obf_o
__device__ void gemm_unit(int epi, int ln,
    const void* __restrict__ Ap,
    const float* __restrict__ lng, const float* __restrict__ lnb,
    const unsigned short* __restrict__ Bt,
    int N, int K,
    const float* __restrict__ bias,
    const float* __restrict__ xin,
    float* __restrict__ xout,
    unsigned short* __restrict__ obf_o,
    unsigned short* __restrict__ qbf,
    unsigned short* __restrict__ kbf,
    unsigned short* __restrict__ vtbf,
    int m0, int n0, char* smem)
{
  unsigned short (*As)[264] = (unsigned short (*)[264])smem;
  unsigned short (*Bs)[264] = (unsigned short (*)[264])(smem + 33792);
  int tid = threadIdx.x, lane = tid & 63, w = tid >> 6;
  int wr = w >> 1, wc = w & 1;
  int row = tid >> 2, q4 = tid & 3;
  int l15 = lane & 15;
  f32x4 acc[2][2] = {};

  for (int k0 = 0; k0 < K; k0 += 256){
    if (ln){
      const float* xrow = (const float*)Ap + (m0+row)*256;
      float s = 0.f, s2 = 0.f;
      #pragma unroll
      for (int j=0;j<8;j++){
        const float* p = xrow + (j*4+q4)*8;
        f32x4 va = *(const f32x4*)p;
        f32x4 vb = *(const f32x4*)(p+4);
        #pragma unroll
        for (int e=0;e<4;e++){ s += va[e]+vb[e]; s2 += va[e]*va[e]+vb[e]*vb[e]; }
      }
      s  += __shfl_xor(s, 1);  s2 += __shfl_xor(s2, 1);
      s  += __shfl_xor(s, 2);  s2 += __shfl_xor(s2, 2);
      float mu = s * (1.f/256.f);
      float inv = rsqrtf(s2*(1.f/256.f) - mu*mu + 1e-5f);
      #pragma unroll
      for (int j=0;j<8;j++){
        int c0 = (j*4+q4)*8;
        const float* p = xrow + c0;
        f32x4 va = *(const f32x4*)p;
        f32x4 vb = *(const f32x4*)(p+4);
        f32x4 ga = *(const f32x4*)&lng[c0], gb = *(const f32x4*)&lng[c0+4];
        f32x4 ba = *(const f32x4*)&lnb[c0], bb = *(const f32x4*)&lnb[c0+4];
        short8 o;
        #pragma unroll
        for (int e=0;e<4;e++){
          o[e]   = (short)f2bf((va[e]-mu)*inv*ga[e] + ba[e]);
          o[4+e] = (short)f2bf((vb[e]-mu)*inv*gb[e] + bb[e]);
        }
        *(short8*)&As[row][c0] = o;
      }
    } else {
      const unsigned short* Arow = (const unsigned short*)Ap + (long)(m0+row)*K + k0;
      #pragma unroll
      for (int j=0;j<8;j++){
        int c0 = (j*4+q4)*8;
        *(short8*)&As[row][c0] = *(const short8*)&Arow[c0];
      }
    }
    {
      const unsigned short* Brow = Bt + (long)(n0+row)*K + k0;
      #pragma unroll
      for (int j=0;j<8;j++){
        int c0 = (j*4+q4)*8;
        *(short8*)&Bs[row][c0] = *(const short8*)&Brow[c0];
      }
    }
    __syncthreads();
    #pragma unroll
    for (int ks=0; ks<8; ks++){
      int kc = ks*32 + (lane>>4)*8;
      short8 a0 = *(const short8*)&As[wr*32 + l15][kc];
      short8 a1 = *(const short8*)&As[wr*32 + 16 + l15][kc];
      short8 b0 = *(const short8*)&Bs[wc*32 + l15][kc];
      short8 b1 = *(const short8*)&Bs[wc*32 + 16 + l15][kc];
      acc[0][0] = mfma16(a0,b0,acc[0][0]);
      acc[0][1] = mfma16(a0,b1,acc[0][1]);
      acc[1][0] = mfma16(a1,b0,acc[1][0]);
      acc[1][1] = mfma16(a1,b1,acc[1][1]);
    }
    __syncthreads();
  }

  #pragma unroll
  for (int rt=0; rt<2; rt++)
  #pragma unroll
  for (int ct=0; ct<2; ct++)
  #pragma unroll
  for (int r=0; r<4; r++){
    int rg = m0 + wr*32 + rt*16 + (lane>>4)*4 + r;
    int cg = n0 + wc*32 + ct*16 + l15;
    float v = acc[rt][ct][r];
    if (epi == 0){
      int which = cg >> 8, h = (cg >> 5) & 7, hd = cg & 31;
      if (which == 0)      qbf[(h*NTOK + rg)*32 + hd] = f2bf(v * 0.17677669529663687f);
      else if (which == 1) kbf[(h*NTOK + rg)*32 + hd] = f2bf(v);
      else                 vtbf[(h*32 + hd)*NTOK + rg] = f2bf(v);
    } else if (epi == 1){
      xout[rg*N + cg] = xin[rg*N + cg] + v + bias[cg];
    } else {
      float t = v + bias[cg];
      float ge = 0.5f * t * (1.f + erff(t * 0.70710678118654752f));
      obf_o[rg*N + cg] = f2bf(ge);
    }
  }
}

// ------------- attention unit (32-row tile, single pass) -------------
__device__ void attn_unit(int tile, int h,
    const unsigned short* __restrict__ qbf,
    const unsigned short* __restrict__ kbf,
    const unsigned short* __restrict__ vtbf,
    const int* __restrict__ mask,
    float* __restrict__ rinv_ws,
    unsigned short* __restrict__ obf,
    char* smem)
{
  float (*P32)[268] = (float (*)[268])smem;                 // 34304 B
  float (*O_red)[32][32] = (float (*)[32][32])smem;          // alias (P32 dead by then)
  float (*reds)[32] = (float (*)[32])(smem + 34304);         // 512 B
  float* rowinv_s = (float*)(smem + 34816);                  // 128 B

  int tid = threadIdx.x, lane = tid & 63, w = tid >> 6;
  int row0 = tile * 32;
  int rblk = row0 >> 9;
  unsigned bits;
  if (rblk < 4) bits = 1u << rblk;
  else {
    bits = 16u;
    #pragma unroll
    for (int m=0; m<4; m++) if (mask[m] == 1) bits |= (1u << m);
  }
  int kk = (lane >> 4) * 8;
  int l15 = lane & 15;
  int rgrp = (lane >> 4) * 4;
  short8 aq0 = *(const short8*)&qbf[(h*NTOK + row0 + l15)*32 + kk];
  short8 aq1 = *(const short8*)&qbf[(h*NTOK + row0 + 16 + l15)*32 + kk];

  float s_[8] = {0,0,0,0,0,0,0,0};
  f32x4 oacc[2][2] = {};
  for (int b=0; b<5; b++){
    if (!((bits >> b) & 1)) continue;
    #pragma unroll
    for (int hf=0; hf<2; hf++){
      #pragma unroll
      for (int ct=0; ct<4; ct++){
        int cl = w*64 + ct*16 + l15;
        short8 bk = *(const short8*)&kbf[(h*NTOK + b*512 + hf*256 + cl)*32 + kk];
        f32x4 s0 = {}; s0 = mfma16(aq0, bk, s0);
        f32x4 s1 = {}; s1 = mfma16(aq1, bk, s1);
        #pragma unroll
        for (int r=0;r<4;r++){
          float e0 = __expf(s0[r]), e1 = __expf(s1[r]);
          s_[r] += e0; s_[4+r] += e1;
          P32[rgrp + r][cl] = e0;
          P32[16 + rgrp + r][cl] = e1;
        }
      }
      __syncthreads();
      #pragma unroll
      for (int ks2=0; ks2<2; ks2++){
        int kb = (w*2 + ks2)*32 + kk;
        f32x4 pa0a = *(const f32x4*)&P32[l15][kb],      pa0b = *(const f32x4*)&P32[l15][kb+4];
        f32x4 pa1a = *(const f32x4*)&P32[16 + l15][kb], pa1b = *(const f32x4*)&P32[16 + l15][kb+4];
        short8 pa0, pa1;
        #pragma unroll
        for (int e=0;e<4;e++){
          pa0[e] = (short)f2bf(pa0a[e]); pa0[4+e] = (short)f2bf(pa0b[e]);
          pa1[e] = (short)f2bf(pa1a[e]); pa1[4+e] = (short)f2bf(pa1b[e]);
        }
        #pragma unroll
        for (int hc=0; hc<2; hc++){
          short8 bv = *(const short8*)&vtbf[(h*32 + hc*16 + l15)*NTOK + b*512 + hf*256 + kb];
          oacc[0][hc] = mfma16(pa0, bv, oacc[0][hc]);
          oacc[1][hc] = mfma16(pa1, bv, oacc[1][hc]);
        }
      }
      __syncthreads();
    }
  }
  #pragma unroll
  for (int msk=1; msk<16; msk<<=1)
    #pragma unroll
    for (int i=0;i<8;i++) s_[i] += __shfl_xor(s_[i], msk);
  if (l15 == 0){
    #pragma unroll
    for (int r=0;r<4;r++){ reds[w][rgrp + r] = s_[r]; reds[w][16 + rgrp + r] = s_[4+r]; }
  }
  __syncthreads();
  if (tid < 32){
    float inv = 1.f / (reds[0][tid] + reds[1][tid] + reds[2][tid] + reds[3][tid]);
    rowinv_s[tid] = inv;
    rinv_ws[h*NTOK + row0 + tid] = inv;
  }
  __syncthreads();
  #pragma unroll
  for (int rt=0; rt<2; rt++)
    #pragma unroll
    for (int hc=0; hc<2; hc++)
      #pragma unroll
      for (int r=0; r<4; r++)
        O_red[w][rt*16 + rgrp + r][hc*16 + l15] = oacc[rt][hc][r];
  __syncthreads();
  #pragma unroll
  for (int i2=0; i2<2; i2++){
    int i = tid + i2*256;
    int rl = i >> 4, c2 = (i & 15) * 2;
    float inv = rowinv_s[rl];
    float o0 = (O_red[0][rl][c2]   + O_red[1][rl][c2]   + O_red[2][rl][c2]   + O_red[3][rl][c2]) * inv;
    float o1 = (O_red[0][rl][c2+1] + O_red[1][rl][c2+1] + O_red[2][rl][c2+1] + O_red[3][rl][c2+1]) * inv;
    unsigned int pk = (unsigned int)f2bf(o0) | ((unsigned int)f2bf(o1) << 16);
    *(unsigned int*)&obf[(row0 + rl)*256 + h*32 + c2] = pk;
  }
}

// ------------- dep checks -------------
__device__ int deps_ready(int u, int* F){
  if (u < 480) return 1;
  if (u < 1120){
    int t = u - 480, tile = t % 80;
    if (tile < 64){
      int cb = tile >> 4;
      #pragma unroll
      for (int s = 0; s < 8; s++) if (ldF(F, QS + 8*cb + s) < 12) return 0;
      return 1;
    }
    return ldF(F, Q_TOT) >= 480;
  }
  if (u < 1280) return ldF(F, AS + (u-1120)/4)  >= 16;
  if (u < 1920) return ldF(F, PS + (u-1280)/16) >= 4;
  return              ldF(F, MS + (u-1920)/4)  >= 16;
}

__device__ int p_ready(int up, const int* mask, int* F){
  int h, tile;
  if (up < 512){ h = up >> 6; tile = up & 63; }
  else if (up < 640){ int v = up - 512; h = v >> 4; tile = 64 + (v & 15); }
  else { int v = up - 640; int cb = v & 3; if (mask[cb] != 1) return 1; h = v >> 6; tile = 64 + ((v >> 2) & 15); }
  return ldF(F, AF + h*80 + tile);
}

__device__ void complete_unit(int u, int* F){
  if (u < 480){ atomicAdd(&F[QS + u/12], 1); atomicAdd(&F[Q_TOT], 1); }
  else if (u < 1120){
    int t = u - 480, tile = t % 80, h = t / 80;
    atomicAdd(&F[AS + (tile >> 1)], 1);
    atomicExch(&F[AF + h*80 + tile], 1);
  }
  else if (u < 1280) atomicAdd(&F[PS + (u-1120)/4], 1);
  else if (u < 1920) atomicAdd(&F[MS + (u-1280)/16], 1);
}

// ------------- per-layer dataflow mega-kernel -------------
__global__ __launch_bounds__(256) void mega_k(
    const float* __restrict__ xsrc, const int* __restrict__ maskp,
    const float* __restrict__ ln1g, const float* __restrict__ ln1b,
    const unsigned short* __restrict__ wqkvt,
    const unsigned short* __restrict__ wprojt, const float* __restrict__ bproj,
    const float* __restrict__ ln2g, const float* __restrict__ ln2b,
    const unsigned short* __restrict__ w1t, const float* __restrict__ b1,
    const unsigned short* __restrict__ w2t, const float* __restrict__ b2,
    unsigned short* __restrict__ qbf, unsigned short* __restrict__ kbf,
    unsigned short* __restrict__ vtbf, float* __restrict__ rinv,
    unsigned short* __restrict__ obf, unsigned short* __restrict__ mbf,
    float* __restrict__ x_mid, float* __restrict__ xout,
    float* __restrict__ attn, int* F)
{
  __shared__ __align__(16) char smem[67584];
  __shared__ int sh[4];   // 0: unit/cargo idx, 1: cargo idx, 2: pending, 3: state
  int tid = threadIdx.x;
  if (tid == 0) sh[2] = -1;
  __syncthreads();

  // exec helpers as lambdas are not allowed in device easily pre-C++17-ext; use macros inline
  for (;;){
    if (tid == 0) sh[0] = atomicAdd(&F[C_CTR], 1);
    __syncthreads();
    int u = sh[0];
    if (u >= NCOMP) break;

    // wait for deps, filling with cargo
    for (;;){
      if (tid == 0){
        int st = 0;
        int p = sh[2];
        if (p >= 0 && p_ready(p - 2560, maskp, F)) st = 2;
        else if (deps_ready(u, F)) st = 1;
        else if (p < 0){
          if (ldF(F, G_CTR) < NCARGO){
            int c = atomicAdd(&F[G_CTR], 1);
            if (c < NCARGO){
              if (c < 2560 || p_ready(c - 2560, maskp, F)){ sh[1] = c; st = 3; }
              else { sh[2] = c; st = 0; }
            }
          }
        }
        sh[3] = st;
      }
      __syncthreads();
      int st = sh[3];
      if (st == 1){ __threadfence(); break; }
      if (st == 2){
        int c = sh[2]; __threadfence();
        if (c < 2560) zero_unit_body(c, maskp, attn);
        else p_unit_body(c - 2560, qbf, kbf, rinv, attn, maskp, smem);
        __syncthreads();
        if (tid == 0) sh[2] = -1;
        __syncthreads();
      } else if (st == 3){
        int c = sh[1]; __threadfence();
        if (c < 2560) zero_unit_body(c, maskp, attn);
        else p_unit_body(c - 2560, qbf, kbf, rinv, attn, maskp, smem);
        __syncthreads();
      } else {
        __builtin_amdgcn_s_sleep(2);
        __syncthreads();
      }
    }

    // execute compute unit u
    if (u < 480){
      int xg = u % 12, yg = u / 12;
      gemm_unit(0, 1, xsrc, ln1g, ln1b, wqkvt, 768, 256,
                nullptr, nullptr, nullptr, nullptr, qbf, kbf, vtbf,
                yg*64, xg*64, smem);
    } else if (u < 1120){
      int t = u - 480, tile = t % 80, h = t / 80;
      attn_unit(tile, h, qbf, kbf, vtbf, maskp, rinv, obf, smem);
    } else if (u < 1280){
      int v = u - 1120, xg = v % 4, yg = v / 4;
      gemm_unit(1, 0, obf, nullptr, nullptr, wprojt, 256, 256,
                bproj, xsrc, x_mid, nullptr, nullptr, nullptr, nullptr,
                yg*64, xg*64, smem);
    } else if (u < 1920){
      int v = u - 1280, xg = v % 16, yg = v / 16;
      gemm_unit(2, 1, x_mid, ln2g, ln2b, w1t, 1024, 256,
                b1, nullptr, nullptr, mbf, nullptr, nullptr, nullptr,
                yg*64, xg*64, smem);
    } else {
      int v = u - 1920, xg = v % 4, yg = v / 4;
      gemm_unit(1, 0, mbf, nullptr, nullptr, w2t, 256, 1024,
                b2, x_mid, xout, nullptr, nullptr, nullptr, nullptr,
                yg*64, xg*64, smem);
    }
    __threadfence();
    __syncthreads();
    if (tid == 0) complete_unit(u, F);
    __syncthreads();
  }

  // drain cargo (flush pending first, then pull remaining)
  for (;;){
    if (tid == 0){
      int st = 0;
      int p = sh[2];
      if (p >= 0){
        if (p_ready(p - 2560, maskp, F)) st = 2;
      } else {
        int c = atomicAdd(&F[G_CTR], 1);
        if (c < NCARGO){
          if (c < 2560 || p_ready(c - 2560, maskp, F)){ sh[1] = c; st = 3; }
          else { sh[2] = c; st = 0; }
        } else st = 4;
      }
      sh[3] = st;
    }
    __syncthreads();
    int st = sh[3];
    if (st == 4) break;
    if (st == 2){
      int c = sh[2]; __threadfence();
      if (c < 2560) zero_unit_body(c, maskp, attn);
      else p_unit_body(c - 2560, qbf, kbf, rinv, attn, maskp, smem);
      __syncthreads();
      if (tid == 0) sh[2] = -1;
      __syncthreads();
    } else if (st == 3){
      int c = sh[1]; __threadfence();
      if (c < 2560) zero_unit_body(c, maskp, attn);
      else p_unit_body(c - 2560, qbf, kbf, rinv, attn, maskp, smem);
      __syncthreads();
    } else {
      __builtin_amdgcn_s_sleep(2);
      __syncthreads();
    }
  }
}

// ---------------- launcher ----------------
extern "C" void kernel_launch(void* const* d_in, const int* in_sizes, int n_in,
                              void* d_out, int out_size, void* d_ws, size_t ws_size,
                              hipStream_t stream)
{
  const float* x_in  = (const float*)d_in[0];
  const int*   maskp = (const int*)d_in[1];
  const float* ln1g  = (const float*)d_in[2];
  const float* ln1b  = (const float*)d_in[3];
  const float* Wqkv  = (const float*)d_in[4];
  const float* Wproj = (const float*)d_in[5];
  const float* bproj = (const float*)d_in[6];
  const float* ln2g  = (const float*)d_in[7];
  const float* ln2b  = (const float*)d_in[8];
  const float* W1    = (const float*)d_in[9];
  const float* b1    = (const float*)d_in[10];
  const float* W2    = (const float*)d_in[11];
  const float* b2    = (const float*)d_in[12];
  float* out = (float*)d_out;

  char* ws = (char*)d_ws;
  float* x              = (float*)(ws + 0);                 // 2560*256 f32
  unsigned short* mbf   = (unsigned short*)(ws + 2621440);  // 2560*1024 bf16
  unsigned short* obf   = (unsigned short*)(ws + 7864320);  // 2560*256 bf16
  unsigned short* qbf   = (unsigned short*)(ws + 9175040);  // 8*2560*32 bf16
  unsigned short* kbf   = (unsigned short*)(ws + 10485760);
  unsigned short* vtbf  = (unsigned short*)(ws + 11796480); // 8*32*2560 bf16
  float* rinv           = (float*)(ws + 13107200);          // 8*2560 f32 (ends 13,189,120)
  int*   flags          = (int*)(ws + 13190144);            // 4 KB
  unsigned short* wqkvt = (unsigned short*)(ws + 13238272); // 2*768*256 bf16
  unsigned short* wprojt= (unsigned short*)(ws + 14024704); // 2*256*256 bf16
  unsigned short* w1t   = (unsigned short*)(ws + 14286848); // 2*1024*256 bf16
  unsigned short* w2t   = (unsigned short*)(ws + 15335424); // 2*256*1024 bf16 (ends 16,384,000)

  wt_all_k<<<384, 256, 0, stream>>>(Wqkv, Wproj, W1, W2, wqkvt, wprojt, w1t, w2t);

  for (int d = 0; d < 2; d++){
    const float* xsrc = d ? x : x_in;
    float* xo = d ? out : x;
    float* attn = out + 655360 + (long)d*52428800;
    hipMemsetAsync(flags, 0, 4096, stream);
    mega_k<<<dim3(512), 256, 0, stream>>>(
        xsrc, maskp,
        ln1g + d*256, ln1b + d*256, wqkvt + d*196608,
        wprojt + d*65536, bproj + d*256,
        ln2g + d*256, ln2b + d*256,
        w1t + d*262144, b1 + d*1024,
        w2t + d*262144, b2 + d*256,
        qbf, kbf, vtbf, rinv, obf, mbf,
        x, xo, attn, flags);
  }
}

// Round 12
// 186.395 us; speedup vs baseline: 10.0523x; 10.0523x over previous
//
#include <hip/hip_runtime.h>

#define NTOK 2560
#define NN ((long)NTOK*NTOK)

typedef __attribute__((ext_vector_type(8))) short short8;
typedef __attribute__((ext_vector_type(4))) float f32x4;

__device__ __forceinline__ unsigned short f2bf(float f){
  union { float f; unsigned int u; } v; v.f = f;
  unsigned int u = v.u + 0x7fffu + ((v.u >> 16) & 1u);
  return (unsigned short)(u >> 16);
}

__device__ __forceinline__ f32x4 mfma16(short8 a, short8 b, f32x4 c){
  return __builtin_amdgcn_mfma_f32_16x16x32_bf16(a, b, c, 0, 0, 0);
}

// ------------- tiled weight transpose: fp32 [K][N] -> bf16 [N][K], 64x64 tiles -------------
__global__ __launch_bounds__(256) void wt_all_k(
    const float* __restrict__ Wqkv, const float* __restrict__ Wproj,
    const float* __restrict__ W1, const float* __restrict__ W2,
    unsigned short* __restrict__ wqkvt, unsigned short* __restrict__ wprojt,
    unsigned short* __restrict__ w1t, unsigned short* __restrict__ w2t)
{
  __shared__ unsigned short T[64][68];
  int j = blockIdx.x;               // < 384
  int d = j >= 192; j -= d*192;
  const float* src; unsigned short* dst; int K, N, tk, tn;
  if (j < 48){        src = Wqkv  + d*196608; dst = wqkvt  + d*196608; K=256;  N=768;  tk=j/12; tn=j-tk*12; }
  else if (j < 64){   j-=48;  src = Wproj + d*65536;  dst = wprojt + d*65536;  K=256;  N=256;  tk=j>>2; tn=j&3; }
  else if (j < 128){  j-=64;  src = W1    + d*262144; dst = w1t    + d*262144; K=256;  N=1024; tk=j>>4; tn=j&15; }
  else {              j-=128; src = W2    + d*262144; dst = w2t    + d*262144; K=1024; N=256;  tk=j>>2; tn=j&3; }
  int k0 = tk*64, n0 = tn*64;
  int r = threadIdx.x >> 2, c0 = (threadIdx.x & 3) * 16;
  const float* p = src + (long)(k0+r)*N + n0 + c0;
  #pragma unroll
  for (int e4 = 0; e4 < 4; e4++){
    f32x4 v = *(const f32x4*)(p + e4*4);
    #pragma unroll
    for (int e = 0; e < 4; e++) T[r][c0 + e4*4 + e] = f2bf(v[e]);
  }
  __syncthreads();
  unsigned short* q = dst + (long)(n0+r)*K + k0 + c0;
  short8 o0, o1;
  #pragma unroll
  for (int e = 0; e < 8; e++){ o0[e] = (short)T[c0+e][r]; o1[e] = (short)T[c0+8+e][r]; }
  *(short8*)q = o0;
  *(short8*)(q+8) = o1;
}

// ------------- P-emission unit: one (head, 32-row tile, 512-col block) -------------
__device__ __forceinline__ void p_unit_body(
    int u, const unsigned short* __restrict__ qbf, const unsigned short* __restrict__ kbf,
    const float* __restrict__ rinv_ws, float* __restrict__ attn_out,
    const int* __restrict__ mask, char* smem)
{
  float (*P32)[268] = (float (*)[268])smem;
  int tid = threadIdx.x, lane = tid & 63, w = tid >> 6;
  int cb = u % 5, t2 = u / 5, tile = t2 % 80, h = t2 / 80;
  int row0 = tile * 32;
  int rblk = row0 >> 9;
  unsigned bits;
  if (rblk < 4) bits = 1u << rblk;
  else {
    bits = 16u;
    #pragma unroll
    for (int m=0; m<4; m++) if (mask[m]==1) bits |= (1u<<m);
  }
  long base = (long)h*NN + (long)row0*NTOK + cb*512;
  if (!((bits >> cb) & 1)){
    f32x4 z = {0.f,0.f,0.f,0.f};
    #pragma unroll
    for (int i=0;i<16;i++){
      int idx = tid + i*256;
      int rl = idx >> 7, c4 = (idx & 127) << 2;
      *(f32x4*)&attn_out[base + (long)rl*NTOK + c4] = z;
    }
    return;
  }
  int kk = (lane>>4)*8, l15 = lane & 15, rgrp = (lane>>4)*4;
  short8 aq0 = *(const short8*)&qbf[(h*NTOK + row0 + l15)*32 + kk];
  short8 aq1 = *(const short8*)&qbf[(h*NTOK + row0 + 16 + l15)*32 + kk];
  float rinv[8];
  #pragma unroll
  for (int r=0;r<4;r++){
    rinv[r]   = rinv_ws[h*NTOK + row0 + rgrp + r];
    rinv[4+r] = rinv_ws[h*NTOK + row0 + 16 + rgrp + r];
  }
  #pragma unroll
  for (int hf=0; hf<2; hf++){
    #pragma unroll
    for (int ct=0; ct<4; ct++){
      int cl = w*64 + ct*16 + l15;
      short8 bk = *(const short8*)&kbf[(h*NTOK + cb*512 + hf*256 + cl)*32 + kk];
      f32x4 s0 = {}; s0 = mfma16(aq0, bk, s0);
      f32x4 s1 = {}; s1 = mfma16(aq1, bk, s1);
      #pragma unroll
      for (int r=0;r<4;r++){
        P32[rgrp + r][cl]      = __expf(s0[r]) * rinv[r];
        P32[16 + rgrp + r][cl] = __expf(s1[r]) * rinv[4+r];
      }
    }
    __syncthreads();
    long hbase = base + hf*256;
    #pragma unroll
    for (int j=0;j<8;j++){
      int qi = j*256 + tid;
      int rl = qi >> 6, qc = (qi & 63)*4;
      *(f32x4*)&attn_out[hbase + (long)rl*NTOK + qc] = *(const f32x4*)&P32[rl][qc];
    }
    __syncthreads();
  }
}

// ------------- 64x64 bf16 MFMA GEMM + optional fused LN + piggybacked P-units -------------
// union LDS: GEMM uses As(33792)+Bs(33792)=67584B; P-unit uses 34304B. Total 67584 -> 2 blocks/CU.
template<int EPI, bool LN>
__global__ __launch_bounds__(256) void gemm2_k(
    const void* __restrict__ Ap,
    const float* __restrict__ lng, const float* __restrict__ lnb,
    const unsigned short* __restrict__ Bt,
    int N, int K,
    const float* __restrict__ bias,
    const float* __restrict__ xin,
    float* __restrict__ xout,
    unsigned short* __restrict__ obf,
    unsigned short* __restrict__ qbf,
    unsigned short* __restrict__ kbf,
    unsigned short* __restrict__ vtbf,
    int gx, int pbase,
    const unsigned short* __restrict__ p_qbf, const unsigned short* __restrict__ p_kbf,
    const float* __restrict__ p_rinv, float* __restrict__ p_attn,
    const int* __restrict__ maskp)
{
  __shared__ __align__(16) char smem[67584];
  if ((int)blockIdx.x >= gx){
    int u = pbase + ((int)blockIdx.x - gx) * (int)gridDim.y + (int)blockIdx.y;
    p_unit_body(u, p_qbf, p_kbf, p_rinv, p_attn, maskp, smem);
    return;
  }
  unsigned short (*As)[264] = (unsigned short (*)[264])smem;
  unsigned short (*Bs)[264] = (unsigned short (*)[264])(smem + 33792);
  int tid = threadIdx.x, lane = tid & 63, w = tid >> 6;
  int wr = w >> 1, wc = w & 1;
  int m0 = blockIdx.y * 64, n0 = blockIdx.x * 64;
  int row = tid >> 2, q4 = tid & 3;
  int l15 = lane & 15;
  f32x4 acc[2][2] = {};

  for (int k0 = 0; k0 < K; k0 += 256){
    if (LN){
      const float* xrow = (const float*)Ap + (m0+row)*256;
      float s = 0.f, s2 = 0.f;
      #pragma unroll
      for (int j=0;j<8;j++){
        const float* p = xrow + (j*4+q4)*8;
        f32x4 va = *(const f32x4*)p;
        f32x4 vb = *(const f32x4*)(p+4);
        #pragma unroll
        for (int e=0;e<4;e++){ s += va[e]+vb[e]; s2 += va[e]*va[e]+vb[e]*vb[e]; }
      }
      s  += __shfl_xor(s, 1);  s2 += __shfl_xor(s2, 1);
      s  += __shfl_xor(s, 2);  s2 += __shfl_xor(s2, 2);
      float mu = s * (1.f/256.f);
      float inv = rsqrtf(s2*(1.f/256.f) - mu*mu + 1e-5f);
      #pragma unroll
      for (int j=0;j<8;j++){
        int c0 = (j*4+q4)*8;
        const float* p = xrow + c0;
        f32x4 va = *(const f32x4*)p;
        f32x4 vb = *(const f32x4*)(p+4);
        f32x4 ga = *(const f32x4*)&lng[c0], gb = *(const f32x4*)&lng[c0+4];
        f32x4 ba = *(const f32x4*)&lnb[c0], bb = *(const f32x4*)&lnb[c0+4];
        short8 o;
        #pragma unroll
        for (int e=0;e<4;e++){
          o[e]   = (short)f2bf((va[e]-mu)*inv*ga[e] + ba[e]);
          o[4+e] = (short)f2bf((vb[e]-mu)*inv*gb[e] + bb[e]);
        }
        *(short8*)&As[row][c0] = o;
      }
    } else {
      const unsigned short* Arow = (const unsigned short*)Ap + (long)(m0+row)*K + k0;
      #pragma unroll
      for (int j=0;j<8;j++){
        int c0 = (j*4+q4)*8;
        *(short8*)&As[row][c0] = *(const short8*)&Arow[c0];
      }
    }
    {
      const unsigned short* Brow = Bt + (long)(n0+row)*K + k0;
      #pragma unroll
      for (int j=0;j<8;j++){
        int c0 = (j*4+q4)*8;
        *(short8*)&Bs[row][c0] = *(const short8*)&Brow[c0];
      }
    }
    __syncthreads();
    #pragma unroll
    for (int ks=0; ks<8; ks++){
      int kc = ks*32 + (lane>>4)*8;
      short8 a0 = *(const short8*)&As[wr*32 + l15][kc];
      short8 a1 = *(const short8*)&As[wr*32 + 16 + l15][kc];
      short8 b0 = *(const short8*)&Bs[wc*32 + l15][kc];
      short8 b1 = *(const short8*)&Bs[wc*32 + 16 + l15][kc];
      acc[0][0] = mfma16(a0,b0,acc[0][0]);
      acc[0][1] = mfma16(a0,b1,acc[0][1]);
      acc[1][0] = mfma16(a1,b0,acc[1][0]);
      acc[1][1] = mfma16(a1,b1,acc[1][1]);
    }
    if (k0 + 256 < K) __syncthreads();
  }

  #pragma unroll
  for (int rt=0; rt<2; rt++)
  #pragma unroll
  for (int ct=0; ct<2; ct++)
  #pragma unroll
  for (int r=0; r<4; r++){
    int rg = m0 + wr*32 + rt*16 + (lane>>4)*4 + r;
    int cg = n0 + wc*32 + ct*16 + l15;
    float v = acc[rt][ct][r];
    if (EPI == 0){
      int which = cg >> 8, h = (cg >> 5) & 7, hd = cg & 31;
      if (which == 0)      qbf[(h*NTOK + rg)*32 + hd] = f2bf(v * 0.17677669529663687f);
      else if (which == 1) kbf[(h*NTOK + rg)*32 + hd] = f2bf(v);
      else                 vtbf[(h*32 + hd)*NTOK + rg] = f2bf(v);
    } else if (EPI == 1){
      xout[rg*N + cg] = xin[rg*N + cg] + v + bias[cg];
    } else {
      float t = v + bias[cg];
      float ge = 0.5f * t * (1.f + erff(t * 0.70710678118654752f));
      obf[rg*N + cg] = f2bf(ge);
    }
  }
}

// ------------- attention core: single pass, no P writes; obf + rinv only -------------
__global__ __launch_bounds__(256) void attn_o_k(
    const unsigned short* __restrict__ qbf,   // [8][2560][32] (q pre-scaled)
    const unsigned short* __restrict__ kbf,   // [8][2560][32]
    const unsigned short* __restrict__ vtbf,  // [8][32][2560]
    const int* __restrict__ mask,             // [4]
    float* __restrict__ rinv_ws,              // [8][2560]
    unsigned short* __restrict__ obf)         // [2560][256] bf16
{
  __shared__ __align__(16) float P32[32][268];
  __shared__ float O_red[4][32][32];
  __shared__ float reds[4][32];
  __shared__ float rowinv_s[32];

  int tid = threadIdx.x, lane = tid & 63, w = tid >> 6;
  int row0 = blockIdx.x * 32, h = blockIdx.y;
  int rblk = row0 >> 9;
  unsigned bits;
  if (rblk < 4) bits = 1u << rblk;
  else {
    bits = 16u;
    #pragma unroll
    for (int m=0; m<4; m++) if (mask[m] == 1) bits |= (1u << m);
  }
  int kk = (lane >> 4) * 8;
  int l15 = lane & 15;
  int rgrp = (lane >> 4) * 4;
  short8 aq0 = *(const short8*)&qbf[(h*NTOK + row0 + l15)*32 + kk];
  short8 aq1 = *(const short8*)&qbf[(h*NTOK + row0 + 16 + l15)*32 + kk];

  float s_[8] = {0,0,0,0,0,0,0,0};
  f32x4 oacc[2][2] = {};
  for (int b=0; b<5; b++){
    if (!((bits >> b) & 1)) continue;
    #pragma unroll
    for (int hf=0; hf<2; hf++){
      #pragma unroll
      for (int ct=0; ct<4; ct++){
        int cl = w*64 + ct*16 + l15;
        short8 bk = *(const short8*)&kbf[(h*NTOK + b*512 + hf*256 + cl)*32 + kk];
        f32x4 s0 = {}; s0 = mfma16(aq0, bk, s0);
        f32x4 s1 = {}; s1 = mfma16(aq1, bk, s1);
        #pragma unroll
        for (int r=0;r<4;r++){
          float e0 = __expf(s0[r]), e1 = __expf(s1[r]);
          s_[r] += e0; s_[4+r] += e1;
          P32[rgrp + r][cl] = e0;
          P32[16 + rgrp + r][cl] = e1;
        }
      }
      __syncthreads();
      #pragma unroll
      for (int ks2=0; ks2<2; ks2++){
        int kb = (w*2 + ks2)*32 + kk;
        f32x4 pa0a = *(const f32x4*)&P32[l15][kb],      pa0b = *(const f32x4*)&P32[l15][kb+4];
        f32x4 pa1a = *(const f32x4*)&P32[16 + l15][kb], pa1b = *(const f32x4*)&P32[16 + l15][kb+4];
        short8 pa0, pa1;
        #pragma unroll
        for (int e=0;e<4;e++){
          pa0[e] = (short)f2bf(pa0a[e]); pa0[4+e] = (short)f2bf(pa0b[e]);
          pa1[e] = (short)f2bf(pa1a[e]); pa1[4+e] = (short)f2bf(pa1b[e]);
        }
        #pragma unroll
        for (int hc=0; hc<2; hc++){
          short8 bv = *(const short8*)&vtbf[(h*32 + hc*16 + l15)*NTOK + b*512 + hf*256 + kb];
          oacc[0][hc] = mfma16(pa0, bv, oacc[0][hc]);
          oacc[1][hc] = mfma16(pa1, bv, oacc[1][hc]);
        }
      }
      __syncthreads();
    }
  }
  #pragma unroll
  for (int msk=1; msk<16; msk<<=1)
    #pragma unroll
    for (int i=0;i<8;i++) s_[i] += __shfl_xor(s_[i], msk);
  if (l15 == 0){
    #pragma unroll
    for (int r=0;r<4;r++){ reds[w][rgrp + r] = s_[r]; reds[w][16 + rgrp + r] = s_[4+r]; }
  }
  __syncthreads();
  if (tid < 32){
    float inv = 1.f / (reds[0][tid] + reds[1][tid] + reds[2][tid] + reds[3][tid]);
    rowinv_s[tid] = inv;
    rinv_ws[h*NTOK + row0 + tid] = inv;
  }
  __syncthreads();
  #pragma unroll
  for (int rt=0; rt<2; rt++)
    #pragma unroll
    for (int hc=0; hc<2; hc++)
      #pragma unroll
      for (int r=0; r<4; r++)
        O_red[w][rt*16 + rgrp + r][hc*16 + l15] = oacc[rt][hc][r];
  __syncthreads();
  #pragma unroll
  for (int i2=0; i2<2; i2++){
    int i = tid + i2*256;
    int rl = i >> 4, c2 = (i & 15) * 2;
    float inv = rowinv_s[rl];
    float o0 = (O_red[0][rl][c2]   + O_red[1][rl][c2]   + O_red[2][rl][c2]   + O_red[3][rl][c2]) * inv;
    float o1 = (O_red[0][rl][c2+1] + O_red[1][rl][c2+1] + O_red[2][rl][c2+1] + O_red[3][rl][c2+1]) * inv;
    unsigned int pk = (unsigned int)f2bf(o0) | ((unsigned int)f2bf(o1) << 16);
    *(unsigned int*)&obf[(row0 + rl)*256 + h*32 + c2] = pk;
  }
}

// ---------------- launcher ----------------
extern "C" void kernel_launch(void* const* d_in, const int* in_sizes, int n_in,
                              void* d_out, int out_size, void* d_ws, size_t ws_size,
                              hipStream_t stream)
{
  const float* x_in  = (const float*)d_in[0];
  const int*   maskp = (const int*)d_in[1];
  const float* ln1g  = (const float*)d_in[2];
  const float* ln1b  = (const float*)d_in[3];
  const float* Wqkv  = (const float*)d_in[4];
  const float* Wproj = (const float*)d_in[5];
  const float* bproj = (const float*)d_in[6];
  const float* ln2g  = (const float*)d_in[7];
  const float* ln2b  = (const float*)d_in[8];
  const float* W1    = (const float*)d_in[9];
  const float* b1    = (const float*)d_in[10];
  const float* W2    = (const float*)d_in[11];
  const float* b2    = (const float*)d_in[12];
  float* out = (float*)d_out;

  char* ws = (char*)d_ws;
  float* x              = (float*)(ws + 0);                 // 2560*256 f32
  unsigned short* mbf   = (unsigned short*)(ws + 2621440);  // 2560*1024 bf16
  unsigned short* obf   = (unsigned short*)(ws + 7864320);  // 2560*256 bf16
  unsigned short* qbf   = (unsigned short*)(ws + 9175040);  // 8*2560*32 bf16
  unsigned short* kbf   = (unsigned short*)(ws + 10485760);
  unsigned short* vtbf  = (unsigned short*)(ws + 11796480); // 8*32*2560 bf16
  float* rinv           = (float*)(ws + 13107200);          // 8*2560 f32
  unsigned short* wqkvt = (unsigned short*)(ws + 13238272); // 2*768*256 bf16
  unsigned short* wprojt= (unsigned short*)(ws + 14024704); // 2*256*256 bf16
  unsigned short* w1t   = (unsigned short*)(ws + 14286848); // 2*1024*256 bf16
  unsigned short* w2t   = (unsigned short*)(ws + 15335424); // 2*256*1024 bf16 (ends 16384000)

  wt_all_k<<<384, 256, 0, stream>>>(Wqkv, Wproj, W1, W2, wqkvt, wprojt, w1t, w2t);

  for (int d=0; d<2; d++){
    const float* xsrc = d ? x : x_in;
    float* attn = out + 655360 + (long)d*52428800;
    // LN1 + QKV
    gemm2_k<0,true><<<dim3(12,40), 256, 0, stream>>>(xsrc, ln1g + d*256, ln1b + d*256,
        wqkvt + d*196608, 768, 256, nullptr, nullptr, nullptr, nullptr, qbf, kbf, vtbf,
        12, 0, nullptr, nullptr, nullptr, nullptr, nullptr);
    // attention core
    attn_o_k<<<dim3(80,8), 256, 0, stream>>>(qbf, kbf, vtbf, maskp, rinv, obf);
    // proj + residual  (+800 P units: 0..799)
    gemm2_k<1,false><<<dim3(24,40), 256, 0, stream>>>(obf, nullptr, nullptr,
        wprojt + d*65536, 256, 256, bproj + d*256, xsrc, x, nullptr, nullptr, nullptr, nullptr,
        4, 0, qbf, kbf, rinv, attn, maskp);
    // LN2 + MLP1 + gelu  (+1200 P units: 800..1999)
    gemm2_k<2,true><<<dim3(46,40), 256, 0, stream>>>(x, ln2g + d*256, ln2b + d*256,
        w1t + d*262144, 1024, 256, b1 + d*1024, nullptr, nullptr, mbf, nullptr, nullptr, nullptr,
        16, 800, qbf, kbf, rinv, attn, maskp);
    // MLP2 + residual  (+1200 P units: 2000..3199)
    float* xo = d ? out : x;
    gemm2_k<1,false><<<dim3(34,40), 256, 0, stream>>>(mbf, nullptr, nullptr,
        w2t + d*262144, 256, 1024, b2 + d*256, x, xo, nullptr, nullptr, nullptr, nullptr,
        4, 2000, qbf, kbf, rinv, attn, maskp);
  }
}